// Round 19
// baseline (134.330 us; speedup 1.0000x reference)
//
#include <hip/hip_runtime.h>
#include <math.h>

// Problem constants (MultiHeadAttention_15341623181946)
#define NB 8          // batch
#define SS 1024       // sequence
#define NH 16         // heads
#define DK 64         // head dim
#define EE 1024       // NH*DK
#define DMOD 1024     // d_model

using bf16x8 = __attribute__((ext_vector_type(8))) short;   // 8 bf16 = 4 VGPR
using f32x4  = __attribute__((ext_vector_type(4))) float;   // MFMA acc (16x16)
using f32x16 = __attribute__((ext_vector_type(16))) float;  // MFMA acc (32x32)

__device__ __forceinline__ unsigned short f2bf(float f) {
    unsigned u = __builtin_bit_cast(unsigned, f);
    u += 0x7FFFu + ((u >> 16) & 1u);        // round-to-nearest-even
    return (unsigned short)(u >> 16);
}

__device__ __forceinline__ float exp2_hw(float x) {
#if __has_builtin(__builtin_amdgcn_exp2f)
    return __builtin_amdgcn_exp2f(x);
#else
    float r; asm("v_exp_f32 %0, %1" : "=v"(r) : "v"(x)); return r;
#endif
}

__device__ __forceinline__ unsigned cvt_pk_bf16(float lo, float hi) {
    unsigned r;
    asm("v_cvt_pk_bf16_f32 %0, %1, %2" : "=v"(r) : "v"(lo), "v"(hi));
    return r;
}

// v_permlane32_swap_b32: dst[i>=32] <-> src[i<32]. Both operands updated.
__device__ __forceinline__ void plane32_swap(unsigned& a, unsigned& b) {
    asm volatile("v_permlane32_swap_b32 %0, %1" : "+v"(a), "+v"(b));
}

// Async global->LDS, 16B per lane. LDS dest must be wave-uniform base;
// HW writes base + lane*16. Global src is per-lane.
__device__ __forceinline__ void gld16(const void* g, void* l) {
    __builtin_amdgcn_global_load_lds(
        (const __attribute__((address_space(1))) void*)g,
        (__attribute__((address_space(3))) void*)l, 16, 0, 0);
}

// ---------------------------------------------------------------------------
// Batched f32 -> bf16 conversion for all tensors that feed MFMA.
// z: 0=W1(1M) 1=W2(1M) 2=q(512K) 3=k 4=v 5=Wq(64K). grid (512, 6).
// ---------------------------------------------------------------------------
__global__ __launch_bounds__(256) void cvt_all(
    const float* __restrict__ W1, const float* __restrict__ W2,
    const float* __restrict__ q, const float* __restrict__ k,
    const float* __restrict__ v, const float* __restrict__ Wq,
    unsigned short* __restrict__ W1b, unsigned short* __restrict__ W2b,
    unsigned short* __restrict__ qb, unsigned short* __restrict__ kb,
    unsigned short* __restrict__ vb, unsigned short* __restrict__ Wqb)
{
    const int z = blockIdx.y;
    const float* s; unsigned short* d; int n;
    switch (z) {
        case 0:  s = W1; d = W1b; n = 1048576; break;
        case 1:  s = W2; d = W2b; n = 1048576; break;
        case 2:  s = q;  d = qb;  n = 524288;  break;
        case 3:  s = k;  d = kb;  n = 524288;  break;
        case 4:  s = v;  d = vb;  n = 524288;  break;
        default: s = Wq; d = Wqb; n = 65536;   break;
    }
    const int i = (blockIdx.x * 256 + threadIdx.x) * 8;
    if (i >= n) return;
    const float4 a = *(const float4*)(s + i);
    const float4 b = *(const float4*)(s + i + 4);
    bf16x8 o;
    o[0]=(short)f2bf(a.x); o[1]=(short)f2bf(a.y); o[2]=(short)f2bf(a.z); o[3]=(short)f2bf(a.w);
    o[4]=(short)f2bf(b.x); o[5]=(short)f2bf(b.y); o[6]=(short)f2bf(b.z); o[7]=(short)f2bf(b.w);
    *(bf16x8*)(d + i) = o;
}

// ---------------------------------------------------------------------------
// Projection GEMM, bf16 MFMA, K=64. z = 0:q (scaled), 1:k, 2:v (TRANSPOSED).
// (Exact R9/R14/R15/R16 version — verified passing.)
// ---------------------------------------------------------------------------
__global__ __launch_bounds__(256) void proj_mfma(
    const unsigned short* __restrict__ qb, const unsigned short* __restrict__ kb,
    const unsigned short* __restrict__ vb, const unsigned short* __restrict__ Wb,
    const float* __restrict__ bias, unsigned short* __restrict__ Cbase,
    float qscale)
{
    __shared__ __align__(16) unsigned short As[128 * 64];
    __shared__ __align__(16) unsigned short Bs[128 * 64];
    const int z = blockIdx.z;
    const unsigned short* X = (z == 0) ? qb : (z == 1) ? kb : vb;
    unsigned short* C = Cbase + (size_t)z * 8388608;
    const float sc = (z == 0) ? qscale : 1.0f;
    const int tid  = threadIdx.x;
    const int lane = tid & 63;
    const int w = tid >> 6, wm = w >> 1, wn = w & 1;
    const int n0 = blockIdx.x * 128, m0 = blockIdx.y * 128;
    const int lr = lane & 15, lg = lane >> 4;

    #pragma unroll
    for (int p = 0; p < 4; ++p) {
        const int c = p * 256 + tid;
        const int lb = (p * 256 + (tid & ~63)) * 8;   // wave-uniform LDS elem base
        gld16(X  + (size_t)m0 * DK + (size_t)c * 8, As + lb);
        gld16(Wb + (size_t)n0 * DK + (size_t)c * 8, Bs + lb);
    }
    __syncthreads();

    f32x4 acc[4][4] = {};
    #pragma unroll
    for (int kk = 0; kk < 2; ++kk) {
        bf16x8 af[4], bfr[4];
        #pragma unroll
        for (int mf = 0; mf < 4; ++mf)
            af[mf] = *(const bf16x8*)&As[(wm * 64 + mf * 16 + lr) * 64 + kk * 32 + lg * 8];
        #pragma unroll
        for (int nf = 0; nf < 4; ++nf)
            bfr[nf] = *(const bf16x8*)&Bs[(wn * 64 + nf * 16 + lr) * 64 + kk * 32 + lg * 8];
        #pragma unroll
        for (int mf = 0; mf < 4; ++mf)
            #pragma unroll
            for (int nf = 0; nf < 4; ++nf)
                acc[mf][nf] = __builtin_amdgcn_mfma_f32_16x16x32_bf16(
                    af[mf], bfr[nf], acc[mf][nf], 0, 0, 0);
    }

    #pragma unroll
    for (int nf = 0; nf < 4; ++nf) {
        const int n = n0 + wn * 64 + nf * 16 + lr;
        const float bb = bias[n];
        #pragma unroll
        for (int mf = 0; mf < 4; ++mf)
            #pragma unroll
            for (int r = 0; r < 4; ++r) {
                const int mr = m0 + wm * 64 + mf * 16 + lg * 4 + r;
                const int bh = (mr >> 10) * NH + (n >> 6);
                const int s  = mr & 1023, d = n & 63;
                const size_t idx = (z == 2)
                    ? (size_t)bh * 65536 + (size_t)d * 1024 + s     // [b][h][d][s]
                    : (size_t)bh * 65536 + (size_t)s * 64 + d;      // [b][h][s][d]
                C[idx] = f2bf((acc[mf][nf][r] + bb) * sc);
            }
    }
}

// ---------------------------------------------------------------------------
// Flash attention v15 (EXACT R16 version — verified passing, 50.3 us; the
// session-best attention). 32x32 MFMA core, T12 permlane P, max-free
// softmax, double-buffered K/V with one barrier per tile, T14 prefetch,
// T2 chunk-XOR swizzle, setprio, bijective XCD swizzle. 4 waves / 256 thr.
// CLOSED levers (all verified-negative this session): 8-wave blocks
// (R7/R11 fail), l-via-MFMA (R18 -6us), KVBLK=128 (R10), wider q/wave
// beyond 32 (VGPR/occupancy), reg-staged K/V (R4).
// ---------------------------------------------------------------------------
__global__ __launch_bounds__(256) void attn_v15(
    const unsigned short* __restrict__ Qp, const unsigned short* __restrict__ Kp,
    const unsigned short* __restrict__ Vt, unsigned short* __restrict__ Y)
{
    __shared__ __align__(16) unsigned short Ks[2][64 * 64];
    __shared__ __align__(16) unsigned short Vs[2][64 * 64];  // rows d, cols k
    const int tid  = threadIdx.x;
    const int lane = tid & 63;
    const int w    = tid >> 6;
    const int flat    = blockIdx.x;                 // 0..1023
    const int logical = (flat & 7) * 128 + (flat >> 3);
    const int qt = logical & 7;                     // q-tile 0..7 (128 rows)
    const int bh = logical >> 3;                    // 0..127
    const int q0 = qt * 128;
    const size_t base = (size_t)bh * (SS * DK);
    const int q31 = lane & 31, hi = lane >> 5;
    const int l7  = lane & 7;                       // swizzle key (row&7)

    const int c0 = tid,       r0 = c0 >> 3, h0 = c0 & 7;
    const int c1 = 256 + tid, r1 = c1 >> 3, h1 = c1 & 7;
    const int lds0 = r0 * 64 + ((h0 ^ (r0 & 7)) << 3);   // swizzled ushort idx
    const int lds1 = r1 * 64 + ((h1 ^ (r1 & 7)) << 3);

    const unsigned short* kbase = Kp + base;
    const unsigned short* vbase = Vt + base;
    bf16x8 kA = *(const bf16x8*)(kbase + (size_t)r0 * DK + h0 * 8);
    bf16x8 kB = *(const bf16x8*)(kbase + (size_t)r1 * DK + h1 * 8);
    bf16x8 vA = *(const bf16x8*)(vbase + (size_t)r0 * SS + h0 * 8);
    bf16x8 vB = *(const bf16x8*)(vbase + (size_t)r1 * SS + h1 * 8);
    *(bf16x8*)&Ks[0][lds0] = kA; *(bf16x8*)&Ks[0][lds1] = kB;
    *(bf16x8*)&Vs[0][lds0] = vA; *(bf16x8*)&Vs[0][lds1] = vB;

    bf16x8 bQ[4];
    {
        const unsigned short* qptr = Qp + base + (size_t)(q0 + w * 32 + q31) * DK;
        #pragma unroll
        for (int ch = 0; ch < 4; ++ch)
            bQ[ch] = *(const bf16x8*)(qptr + ch * 16 + hi * 8);
    }

    __syncthreads();

    float lacc = 0.0f;          // partial sum of P for q = q31 (hi-half split)
    f32x16 oacc[2] = {};        // [db]: O[q=(r&3)+8*(r>>2)+4*hi][d=32*db+q31]

    for (int kt = 0; kt < 16; ++kt) {
        const int cur = kt & 1;
        const unsigned short* KsC = Ks[cur];
        const unsigned short* VsC = Vs[cur];

        if (kt < 15) {
            const int s1 = (kt + 1) * 64;
            kA = *(const bf16x8*)(kbase + (size_t)(s1 + r0) * DK + h0 * 8);
            kB = *(const bf16x8*)(kbase + (size_t)(s1 + r1) * DK + h1 * 8);
            vA = *(const bf16x8*)(vbase + (size_t)r0 * SS + s1 + h0 * 8);
            vB = *(const bf16x8*)(vbase + (size_t)r1 * SS + s1 + h1 * 8);
        }

        f32x16 sacc[2];
        #pragma unroll
        for (int kb = 0; kb < 2; ++kb) {
            bf16x8 aK[4];
            #pragma unroll
            for (int ch = 0; ch < 4; ++ch) {
                const int row = kb * 32 + q31;
                aK[ch] = *(const bf16x8*)&KsC[row * 64 + (((2 * ch + hi) ^ l7) << 3)];
            }
            f32x16 z = {};
            __builtin_amdgcn_s_setprio(1);
            #pragma unroll
            for (int ch = 0; ch < 4; ++ch)
                z = __builtin_amdgcn_mfma_f32_32x32x16_bf16(aK[ch], bQ[ch], z, 0, 0, 0);
            __builtin_amdgcn_s_setprio(0);
            sacc[kb] = z;
        }

        bf16x8 pa[2][2];   // [kb][cc]: PV A-operand fragments
        #pragma unroll
        for (int kb = 0; kb < 2; ++kb) {
            float p[16];
            float ls = 0.0f;
            #pragma unroll
            for (int r = 0; r < 16; ++r) {
                p[r] = exp2_hw(sacc[kb][r]);
                ls += p[r];
            }
            lacc += ls;
            unsigned D[8];
            #pragma unroll
            for (int u = 0; u < 8; ++u)
                D[u] = cvt_pk_bf16(p[2 * u], p[2 * u + 1]);
            plane32_swap(D[0], D[2]);
            plane32_swap(D[1], D[3]);
            plane32_swap(D[4], D[6]);
            plane32_swap(D[5], D[7]);
            uint4 w0; w0.x = D[0]; w0.y = D[1]; w0.z = D[2]; w0.w = D[3];
            uint4 w1; w1.x = D[4]; w1.y = D[5]; w1.z = D[6]; w1.w = D[7];
            pa[kb][0] = __builtin_bit_cast(bf16x8, w0);
            pa[kb][1] = __builtin_bit_cast(bf16x8, w1);
        }

        __builtin_amdgcn_s_setprio(1);
        #pragma unroll
        for (int db = 0; db < 2; ++db) {
            #pragma unroll
            for (int c = 0; c < 4; ++c) {        // global kdim chunk
                const int row = db * 32 + q31;   // Vs row = d
                const bf16x8 bV = *(const bf16x8*)&VsC[row * 64 + (((2 * c + hi) ^ l7) << 3)];
                oacc[db] = __builtin_amdgcn_mfma_f32_32x32x16_bf16(
                    pa[c >> 1][c & 1], bV, oacc[db], 0, 0, 0);
            }
        }
        __builtin_amdgcn_s_setprio(0);

        if (kt < 15) {
            *(bf16x8*)&Ks[cur ^ 1][lds0] = kA; *(bf16x8*)&Ks[cur ^ 1][lds1] = kB;
            *(bf16x8*)&Vs[cur ^ 1][lds0] = vA; *(bf16x8*)&Vs[cur ^ 1][lds1] = vB;
            __syncthreads();
        }
    }

    // epilogue: l = sum over both hi halves; per-row 1/l broadcast; store
    const int hh = bh & 15, bb = bh >> 4;
    float l = lacc;
    l += __shfl_xor(l, 32);
    const float linv = 1.0f / l;               // valid for q = q31 (both halves)
    #pragma unroll
    for (int r = 0; r < 16; ++r) {
        const int qrl = (r & 3) + 8 * (r >> 2) + 4 * hi;
        const float lri = __shfl(linv, qrl, 32);   // lane qrl within own half
        const int qr = q0 + w * 32 + qrl;
        unsigned short* dst = Y + (size_t)(bb * SS + qr) * EE + hh * DK + q31;
        dst[0]  = f2bf(oacc[0][r] * lri);
        dst[32] = f2bf(oacc[1][r] * lri);
    }
}

// ---------------------------------------------------------------------------
// MLP GEMM, bf16 MFMA, DOUBLE-BUFFERED via global_load_lds (EXACT R16
// version — verified): prefetch tile k+1 into buf^1 before computing tile
// k; one barrier per iteration. 128x128 tile, 4 waves, K-step 64,
// bijective XCD swizzle.
// CLOSED levers: reg-staging (R17 -6us), 64x128 tile (R12 -13us).
// ---------------------------------------------------------------------------
template<bool RELU, bool OUT_BF16>
__global__ __launch_bounds__(256) void mlp_gemm(
    const unsigned short* __restrict__ A, const unsigned short* __restrict__ B,
    const float* __restrict__ bias, void* __restrict__ Cv)
{
    constexpr int K = 1024, N = 1024;
    __shared__ __align__(16) unsigned short As[2][128 * 64];
    __shared__ __align__(16) unsigned short Bs[2][128 * 64];
    const int tid  = threadIdx.x;
    const int lane = tid & 63;
    const int w = tid >> 6, wm = w >> 1, wn = w & 1;
    // bijective XCD swizzle: 512 blocks, 64/XCD = 8 M-tiles x 8 N-tiles
    const int flat    = blockIdx.x;
    const int logical = (flat & 7) * 64 + (flat >> 3);
    const int n0 = (logical & 7) * 128, m0 = (logical >> 3) * 128;
    const int lr = lane & 15, lg = lane >> 4;

    // prologue: stage tile 0 into buf 0
    #pragma unroll
    for (int p = 0; p < 4; ++p) {
        const int c = p * 256 + tid;
        const int row = c >> 3, col = (c & 7) * 8;
        const int lb = (p * 256 + (tid & ~63)) * 8;   // wave-uniform LDS base
        gld16(A + (size_t)(m0 + row) * K + col, As[0] + lb);
        gld16(B + (size_t)(n0 + row) * K + col, Bs[0] + lb);
    }
    __syncthreads();                           // tile 0 ready (vmcnt drained)

    f32x4 acc[4][4] = {};

    #pragma unroll
    for (int kt = 0; kt < 16; ++kt) {
        const int cur = kt & 1;                // compile-time (full unroll)
        if (kt < 15) {
            const int ko = (kt + 1) * 64;
            #pragma unroll
            for (int p = 0; p < 4; ++p) {
                const int c = p * 256 + tid;
                const int row = c >> 3, col = (c & 7) * 8;
                const int lb = (p * 256 + (tid & ~63)) * 8;
                gld16(A + (size_t)(m0 + row) * K + ko + col, As[cur ^ 1] + lb);
                gld16(B + (size_t)(n0 + row) * K + ko + col, Bs[cur ^ 1] + lb);
            }
        }
        #pragma unroll
        for (int kk = 0; kk < 2; ++kk) {
            bf16x8 af[4], bfr[4];
            #pragma unroll
            for (int mf = 0; mf < 4; ++mf)
                af[mf] = *(const bf16x8*)&As[cur][(wm * 64 + mf * 16 + lr) * 64 + kk * 32 + lg * 8];
            #pragma unroll
            for (int nf = 0; nf < 4; ++nf)
                bfr[nf] = *(const bf16x8*)&Bs[cur][(wn * 64 + nf * 16 + lr) * 64 + kk * 32 + lg * 8];
            #pragma unroll
            for (int mf = 0; mf < 4; ++mf)
                #pragma unroll
                for (int nf = 0; nf < 4; ++nf)
                    acc[mf][nf] = __builtin_amdgcn_mfma_f32_16x16x32_bf16(
                        af[mf], bfr[nf], acc[mf][nf], 0, 0, 0);
        }
        __syncthreads();
    }

    #pragma unroll
    for (int nf = 0; nf < 4; ++nf) {
        const int cc = n0 + wn * 64 + nf * 16 + lr;
        const float bb = bias[cc];
        #pragma unroll
        for (int mf = 0; mf < 4; ++mf) {
            #pragma unroll
            for (int r = 0; r < 4; ++r) {
                float x = acc[mf][nf][r] + bb;
                if (RELU) x = fmaxf(x, 0.0f);
                const size_t rr = (size_t)(m0 + wm * 64 + mf * 16 + lg * 4 + r);
                if (OUT_BF16) ((unsigned short*)Cv)[rr * N + cc] = f2bf(x);
                else          ((float*)Cv)[rr * N + cc] = x;
            }
        }
    }
}

// ---------------------------------------------------------------------------
// Workspace layout (ushort elements):
//   Qp : [0        , 8388608 )  -> reused as H1 after attention
//   Kp : [8388608  , 16777216)
//   Vt : [16777216 , 25165824)  (projection z=2 writes [b][h][d][s] directly)
//   Y  : [25165824 , 33554432)
//   W1b: [33554432 , 34603008)
//   W2b: [34603008 , 35651584)
//   qb : [35651584 , 36175872)
//   kb : [36175872 , 36700160)
//   vb : [36700160 , 37224448)
//   Wqb: [37224448 , 37289984)   total ~74.6 MB
// ---------------------------------------------------------------------------
extern "C" void kernel_launch(void* const* d_in, const int* in_sizes, int n_in,
                              void* d_out, int out_size, void* d_ws, size_t ws_size,
                              hipStream_t stream) {
    const float* q  = (const float*)d_in[0];
    const float* k  = (const float*)d_in[1];
    const float* v  = (const float*)d_in[2];
    const float* Wq = (const float*)d_in[3];
    const float* bq = (const float*)d_in[4];
    const float* W1 = (const float*)d_in[5];
    const float* b1 = (const float*)d_in[6];
    const float* W2 = (const float*)d_in[7];
    const float* b2 = (const float*)d_in[8];

    unsigned short* wsu = (unsigned short*)d_ws;
    unsigned short* Qp  = wsu;
    unsigned short* Kp  = wsu + (size_t)8388608;
    unsigned short* Vt  = wsu + (size_t)16777216;
    unsigned short* Y   = wsu + (size_t)25165824;
    unsigned short* W1b = wsu + (size_t)33554432;
    unsigned short* W2b = wsu + (size_t)34603008;
    unsigned short* qb  = wsu + (size_t)35651584;
    unsigned short* kb  = wsu + (size_t)36175872;
    unsigned short* vb  = wsu + (size_t)36700160;
    unsigned short* Wqb = wsu + (size_t)37224448;
    unsigned short* H1  = Qp;   // Qp dead after attention

    dim3 blk(256);

    cvt_all<<<dim3(512, 6), blk, 0, stream>>>(W1, W2, q, k, v, Wq,
                                              W1b, W2b, qb, kb, vb, Wqb);

    // folds 1/sqrt(dk)=0.125 and log2(e) into Q so attn uses v_exp_f32 directly
    const float qscale = 0.125f * 1.44269504088896340736f;
    proj_mfma<<<dim3(8, 64, 3), blk, 0, stream>>>(qb, kb, vb, Wqb, bq, Qp, qscale);

    attn_v15<<<1024, blk, 0, stream>>>(Qp, Kp, Vt, Y);

    mlp_gemm<true,  true ><<<512, blk, 0, stream>>>(Y,  W1b, b1, H1);
    mlp_gemm<false, false><<<512, blk, 0, stream>>>(H1, W2b, b2, d_out);
}

// Round 20
// 133.197 us; speedup vs baseline: 1.0085x; 1.0085x over previous
//
#include <hip/hip_runtime.h>
#include <math.h>

// Problem constants (MultiHeadAttention_15341623181946)
#define NB 8          // batch
#define SS 1024       // sequence
#define NH 16         // heads
#define DK 64         // head dim
#define EE 1024       // NH*DK
#define DMOD 1024     // d_model

using bf16x8 = __attribute__((ext_vector_type(8))) short;   // 8 bf16 = 4 VGPR
using f32x4  = __attribute__((ext_vector_type(4))) float;   // MFMA acc (16x16)
using f32x16 = __attribute__((ext_vector_type(16))) float;  // MFMA acc (32x32)

__device__ __forceinline__ unsigned short f2bf(float f) {
    unsigned u = __builtin_bit_cast(unsigned, f);
    u += 0x7FFFu + ((u >> 16) & 1u);        // round-to-nearest-even
    return (unsigned short)(u >> 16);
}

__device__ __forceinline__ float exp2_hw(float x) {
#if __has_builtin(__builtin_amdgcn_exp2f)
    return __builtin_amdgcn_exp2f(x);
#else
    float r; asm("v_exp_f32 %0, %1" : "=v"(r) : "v"(x)); return r;
#endif
}

__device__ __forceinline__ unsigned cvt_pk_bf16(float lo, float hi) {
    unsigned r;
    asm("v_cvt_pk_bf16_f32 %0, %1, %2" : "=v"(r) : "v"(lo), "v"(hi));
    return r;
}

// v_permlane32_swap_b32: dst[i>=32] <-> src[i<32]. Both operands updated.
__device__ __forceinline__ void plane32_swap(unsigned& a, unsigned& b) {
    asm volatile("v_permlane32_swap_b32 %0, %1" : "+v"(a), "+v"(b));
}

// Async global->LDS, 16B per lane. LDS dest must be wave-uniform base;
// HW writes base + lane*16. Global src is per-lane.
__device__ __forceinline__ void gld16(const void* g, void* l) {
    __builtin_amdgcn_global_load_lds(
        (const __attribute__((address_space(1))) void*)g,
        (__attribute__((address_space(3))) void*)l, 16, 0, 0);
}

__device__ __forceinline__ void cvt8(const float* __restrict__ s,
                                     unsigned short* __restrict__ d, int i) {
    const float4 a = *(const float4*)(s + i);
    const float4 b = *(const float4*)(s + i + 4);
    bf16x8 o;
    o[0]=(short)f2bf(a.x); o[1]=(short)f2bf(a.y); o[2]=(short)f2bf(a.z); o[3]=(short)f2bf(a.w);
    o[4]=(short)f2bf(b.x); o[5]=(short)f2bf(b.y); o[6]=(short)f2bf(b.z); o[7]=(short)f2bf(b.w);
    *(bf16x8*)(d + i) = o;
}

// ---------------------------------------------------------------------------
// Pre-projection f32 -> bf16: ONLY the tensors proj needs (q, k, v, Wq).
// W1/W2 conversion is folded into the attention launch (rides under attn's
// idle HBM bandwidth; W1b/W2b first consumed by mlp1 which launches later).
// grid (256, 4): z=0:q 1:k 2:v (512K each) 3:Wq (64K, first 32 blocks).
// ---------------------------------------------------------------------------
__global__ __launch_bounds__(256) void cvt_pre(
    const float* __restrict__ q, const float* __restrict__ k,
    const float* __restrict__ v, const float* __restrict__ Wq,
    unsigned short* __restrict__ qb, unsigned short* __restrict__ kb,
    unsigned short* __restrict__ vb, unsigned short* __restrict__ Wqb)
{
    const int z = blockIdx.y;
    const float* s; unsigned short* d; int n;
    switch (z) {
        case 0:  s = q;  d = qb;  n = 524288; break;
        case 1:  s = k;  d = kb;  n = 524288; break;
        case 2:  s = v;  d = vb;  n = 524288; break;
        default: s = Wq; d = Wqb; n = 65536;  break;
    }
    const int i = (blockIdx.x * 256 + threadIdx.x) * 8;
    if (i >= n) return;
    cvt8(s, d, i);
}

// ---------------------------------------------------------------------------
// Projection GEMM, bf16 MFMA, K=64. z = 0:q (scaled), 1:k, 2:v (TRANSPOSED).
// (Exact R9/R14/R15/R16 version — verified passing.)
// ---------------------------------------------------------------------------
__global__ __launch_bounds__(256) void proj_mfma(
    const unsigned short* __restrict__ qb, const unsigned short* __restrict__ kb,
    const unsigned short* __restrict__ vb, const unsigned short* __restrict__ Wb,
    const float* __restrict__ bias, unsigned short* __restrict__ Cbase,
    float qscale)
{
    __shared__ __align__(16) unsigned short As[128 * 64];
    __shared__ __align__(16) unsigned short Bs[128 * 64];
    const int z = blockIdx.z;
    const unsigned short* X = (z == 0) ? qb : (z == 1) ? kb : vb;
    unsigned short* C = Cbase + (size_t)z * 8388608;
    const float sc = (z == 0) ? qscale : 1.0f;
    const int tid  = threadIdx.x;
    const int lane = tid & 63;
    const int w = tid >> 6, wm = w >> 1, wn = w & 1;
    const int n0 = blockIdx.x * 128, m0 = blockIdx.y * 128;
    const int lr = lane & 15, lg = lane >> 4;

    #pragma unroll
    for (int p = 0; p < 4; ++p) {
        const int c = p * 256 + tid;
        const int lb = (p * 256 + (tid & ~63)) * 8;   // wave-uniform LDS elem base
        gld16(X  + (size_t)m0 * DK + (size_t)c * 8, As + lb);
        gld16(Wb + (size_t)n0 * DK + (size_t)c * 8, Bs + lb);
    }
    __syncthreads();

    f32x4 acc[4][4] = {};
    #pragma unroll
    for (int kk = 0; kk < 2; ++kk) {
        bf16x8 af[4], bfr[4];
        #pragma unroll
        for (int mf = 0; mf < 4; ++mf)
            af[mf] = *(const bf16x8*)&As[(wm * 64 + mf * 16 + lr) * 64 + kk * 32 + lg * 8];
        #pragma unroll
        for (int nf = 0; nf < 4; ++nf)
            bfr[nf] = *(const bf16x8*)&Bs[(wn * 64 + nf * 16 + lr) * 64 + kk * 32 + lg * 8];
        #pragma unroll
        for (int mf = 0; mf < 4; ++mf)
            #pragma unroll
            for (int nf = 0; nf < 4; ++nf)
                acc[mf][nf] = __builtin_amdgcn_mfma_f32_16x16x32_bf16(
                    af[mf], bfr[nf], acc[mf][nf], 0, 0, 0);
    }

    #pragma unroll
    for (int nf = 0; nf < 4; ++nf) {
        const int n = n0 + wn * 64 + nf * 16 + lr;
        const float bb = bias[n];
        #pragma unroll
        for (int mf = 0; mf < 4; ++mf)
            #pragma unroll
            for (int r = 0; r < 4; ++r) {
                const int mr = m0 + wm * 64 + mf * 16 + lg * 4 + r;
                const int bh = (mr >> 10) * NH + (n >> 6);
                const int s  = mr & 1023, d = n & 63;
                const size_t idx = (z == 2)
                    ? (size_t)bh * 65536 + (size_t)d * 1024 + s     // [b][h][d][s]
                    : (size_t)bh * 65536 + (size_t)s * 64 + d;      // [b][h][s][d]
                C[idx] = f2bf((acc[mf][nf][r] + bb) * sc);
            }
    }
}

// ---------------------------------------------------------------------------
// Flash attention v15 FUSED: blocks [0,1024) run the EXACT R16 attn body
// (verified passing, 50.3 us); blocks [1024,2048) convert W1/W2 to bf16
// (rides under attn's idle HBM BW; consumed only by mlp1, which launches
// after this kernel completes). Per-block-uniform branch, no LDS/barrier
// interaction between the two roles.
// ---------------------------------------------------------------------------
__global__ __launch_bounds__(256) void attn_v15f(
    const unsigned short* __restrict__ Qp, const unsigned short* __restrict__ Kp,
    const unsigned short* __restrict__ Vt, unsigned short* __restrict__ Y,
    const float* __restrict__ W1, const float* __restrict__ W2,
    unsigned short* __restrict__ W1b, unsigned short* __restrict__ W2b)
{
    const int flat = blockIdx.x;
    if (flat >= 1024) {
        // ---- W1/W2 cvt role: ci 0..511 -> W1, 512..1023 -> W2 ----
        const int ci = flat - 1024;
        const float* s = (ci < 512) ? W1 : W2;
        unsigned short* d = (ci < 512) ? W1b : W2b;
        const int i = ((ci & 511) * 256 + (int)threadIdx.x) * 8;   // 512*2048 = 1M
        cvt8(s, d, i);
        return;
    }

    __shared__ __align__(16) unsigned short Ks[2][64 * 64];
    __shared__ __align__(16) unsigned short Vs[2][64 * 64];  // rows d, cols k
    const int tid  = threadIdx.x;
    const int lane = tid & 63;
    const int w    = tid >> 6;
    const int logical = (flat & 7) * 128 + (flat >> 3);
    const int qt = logical & 7;                     // q-tile 0..7 (128 rows)
    const int bh = logical >> 3;                    // 0..127
    const int q0 = qt * 128;
    const size_t base = (size_t)bh * (SS * DK);
    const int q31 = lane & 31, hi = lane >> 5;
    const int l7  = lane & 7;                       // swizzle key (row&7)

    const int c0 = tid,       r0 = c0 >> 3, h0 = c0 & 7;
    const int c1 = 256 + tid, r1 = c1 >> 3, h1 = c1 & 7;
    const int lds0 = r0 * 64 + ((h0 ^ (r0 & 7)) << 3);   // swizzled ushort idx
    const int lds1 = r1 * 64 + ((h1 ^ (r1 & 7)) << 3);

    const unsigned short* kbase = Kp + base;
    const unsigned short* vbase = Vt + base;
    bf16x8 kA = *(const bf16x8*)(kbase + (size_t)r0 * DK + h0 * 8);
    bf16x8 kB = *(const bf16x8*)(kbase + (size_t)r1 * DK + h1 * 8);
    bf16x8 vA = *(const bf16x8*)(vbase + (size_t)r0 * SS + h0 * 8);
    bf16x8 vB = *(const bf16x8*)(vbase + (size_t)r1 * SS + h1 * 8);
    *(bf16x8*)&Ks[0][lds0] = kA; *(bf16x8*)&Ks[0][lds1] = kB;
    *(bf16x8*)&Vs[0][lds0] = vA; *(bf16x8*)&Vs[0][lds1] = vB;

    bf16x8 bQ[4];
    {
        const unsigned short* qptr = Qp + base + (size_t)(q0 + w * 32 + q31) * DK;
        #pragma unroll
        for (int ch = 0; ch < 4; ++ch)
            bQ[ch] = *(const bf16x8*)(qptr + ch * 16 + hi * 8);
    }

    __syncthreads();

    float lacc = 0.0f;          // partial sum of P for q = q31 (hi-half split)
    f32x16 oacc[2] = {};        // [db]: O[q=(r&3)+8*(r>>2)+4*hi][d=32*db+q31]

    for (int kt = 0; kt < 16; ++kt) {
        const int cur = kt & 1;
        const unsigned short* KsC = Ks[cur];
        const unsigned short* VsC = Vs[cur];

        if (kt < 15) {
            const int s1 = (kt + 1) * 64;
            kA = *(const bf16x8*)(kbase + (size_t)(s1 + r0) * DK + h0 * 8);
            kB = *(const bf16x8*)(kbase + (size_t)(s1 + r1) * DK + h1 * 8);
            vA = *(const bf16x8*)(vbase + (size_t)r0 * SS + s1 + h0 * 8);
            vB = *(const bf16x8*)(vbase + (size_t)r1 * SS + s1 + h1 * 8);
        }

        f32x16 sacc[2];
        #pragma unroll
        for (int kb = 0; kb < 2; ++kb) {
            bf16x8 aK[4];
            #pragma unroll
            for (int ch = 0; ch < 4; ++ch) {
                const int row = kb * 32 + q31;
                aK[ch] = *(const bf16x8*)&KsC[row * 64 + (((2 * ch + hi) ^ l7) << 3)];
            }
            f32x16 z = {};
            __builtin_amdgcn_s_setprio(1);
            #pragma unroll
            for (int ch = 0; ch < 4; ++ch)
                z = __builtin_amdgcn_mfma_f32_32x32x16_bf16(aK[ch], bQ[ch], z, 0, 0, 0);
            __builtin_amdgcn_s_setprio(0);
            sacc[kb] = z;
        }

        bf16x8 pa[2][2];   // [kb][cc]: PV A-operand fragments
        #pragma unroll
        for (int kb = 0; kb < 2; ++kb) {
            float p[16];
            float ls = 0.0f;
            #pragma unroll
            for (int r = 0; r < 16; ++r) {
                p[r] = exp2_hw(sacc[kb][r]);
                ls += p[r];
            }
            lacc += ls;
            unsigned D[8];
            #pragma unroll
            for (int u = 0; u < 8; ++u)
                D[u] = cvt_pk_bf16(p[2 * u], p[2 * u + 1]);
            plane32_swap(D[0], D[2]);
            plane32_swap(D[1], D[3]);
            plane32_swap(D[4], D[6]);
            plane32_swap(D[5], D[7]);
            uint4 w0; w0.x = D[0]; w0.y = D[1]; w0.z = D[2]; w0.w = D[3];
            uint4 w1; w1.x = D[4]; w1.y = D[5]; w1.z = D[6]; w1.w = D[7];
            pa[kb][0] = __builtin_bit_cast(bf16x8, w0);
            pa[kb][1] = __builtin_bit_cast(bf16x8, w1);
        }

        __builtin_amdgcn_s_setprio(1);
        #pragma unroll
        for (int db = 0; db < 2; ++db) {
            #pragma unroll
            for (int c = 0; c < 4; ++c) {        // global kdim chunk
                const int row = db * 32 + q31;   // Vs row = d
                const bf16x8 bV = *(const bf16x8*)&VsC[row * 64 + (((2 * c + hi) ^ l7) << 3)];
                oacc[db] = __builtin_amdgcn_mfma_f32_32x32x16_bf16(
                    pa[c >> 1][c & 1], bV, oacc[db], 0, 0, 0);
            }
        }
        __builtin_amdgcn_s_setprio(0);

        if (kt < 15) {
            *(bf16x8*)&Ks[cur ^ 1][lds0] = kA; *(bf16x8*)&Ks[cur ^ 1][lds1] = kB;
            *(bf16x8*)&Vs[cur ^ 1][lds0] = vA; *(bf16x8*)&Vs[cur ^ 1][lds1] = vB;
            __syncthreads();
        }
    }

    // epilogue: l = sum over both hi halves; per-row 1/l broadcast; store
    const int hh = bh & 15, bb = bh >> 4;
    float l = lacc;
    l += __shfl_xor(l, 32);
    const float linv = 1.0f / l;               // valid for q = q31 (both halves)
    #pragma unroll
    for (int r = 0; r < 16; ++r) {
        const int qrl = (r & 3) + 8 * (r >> 2) + 4 * hi;
        const float lri = __shfl(linv, qrl, 32);   // lane qrl within own half
        const int qr = q0 + w * 32 + qrl;
        unsigned short* dst = Y + (size_t)(bb * SS + qr) * EE + hh * DK + q31;
        dst[0]  = f2bf(oacc[0][r] * lri);
        dst[32] = f2bf(oacc[1][r] * lri);
    }
}

// ---------------------------------------------------------------------------
// MLP GEMM, bf16 MFMA, DOUBLE-BUFFERED via global_load_lds (EXACT R16
// version — verified): prefetch tile k+1 into buf^1 before computing tile
// k; one barrier per iteration. 128x128 tile, 4 waves, K-step 64,
// bijective XCD swizzle.
// CLOSED levers: reg-staging (R17 -6us), 64x128 tile (R12 -13us).
// ---------------------------------------------------------------------------
template<bool RELU, bool OUT_BF16>
__global__ __launch_bounds__(256) void mlp_gemm(
    const unsigned short* __restrict__ A, const unsigned short* __restrict__ B,
    const float* __restrict__ bias, void* __restrict__ Cv)
{
    constexpr int K = 1024, N = 1024;
    __shared__ __align__(16) unsigned short As[2][128 * 64];
    __shared__ __align__(16) unsigned short Bs[2][128 * 64];
    const int tid  = threadIdx.x;
    const int lane = tid & 63;
    const int w = tid >> 6, wm = w >> 1, wn = w & 1;
    // bijective XCD swizzle: 512 blocks, 64/XCD = 8 M-tiles x 8 N-tiles
    const int flat    = blockIdx.x;
    const int logical = (flat & 7) * 64 + (flat >> 3);
    const int n0 = (logical & 7) * 128, m0 = (logical >> 3) * 128;
    const int lr = lane & 15, lg = lane >> 4;

    // prologue: stage tile 0 into buf 0
    #pragma unroll
    for (int p = 0; p < 4; ++p) {
        const int c = p * 256 + tid;
        const int row = c >> 3, col = (c & 7) * 8;
        const int lb = (p * 256 + (tid & ~63)) * 8;   // wave-uniform LDS base
        gld16(A + (size_t)(m0 + row) * K + col, As[0] + lb);
        gld16(B + (size_t)(n0 + row) * K + col, Bs[0] + lb);
    }
    __syncthreads();                           // tile 0 ready (vmcnt drained)

    f32x4 acc[4][4] = {};

    #pragma unroll
    for (int kt = 0; kt < 16; ++kt) {
        const int cur = kt & 1;                // compile-time (full unroll)
        if (kt < 15) {
            const int ko = (kt + 1) * 64;
            #pragma unroll
            for (int p = 0; p < 4; ++p) {
                const int c = p * 256 + tid;
                const int row = c >> 3, col = (c & 7) * 8;
                const int lb = (p * 256 + (tid & ~63)) * 8;
                gld16(A + (size_t)(m0 + row) * K + ko + col, As[cur ^ 1] + lb);
                gld16(B + (size_t)(n0 + row) * K + ko + col, Bs[cur ^ 1] + lb);
            }
        }
        #pragma unroll
        for (int kk = 0; kk < 2; ++kk) {
            bf16x8 af[4], bfr[4];
            #pragma unroll
            for (int mf = 0; mf < 4; ++mf)
                af[mf] = *(const bf16x8*)&As[cur][(wm * 64 + mf * 16 + lr) * 64 + kk * 32 + lg * 8];
            #pragma unroll
            for (int nf = 0; nf < 4; ++nf)
                bfr[nf] = *(const bf16x8*)&Bs[cur][(wn * 64 + nf * 16 + lr) * 64 + kk * 32 + lg * 8];
            #pragma unroll
            for (int mf = 0; mf < 4; ++mf)
                #pragma unroll
                for (int nf = 0; nf < 4; ++nf)
                    acc[mf][nf] = __builtin_amdgcn_mfma_f32_16x16x32_bf16(
                        af[mf], bfr[nf], acc[mf][nf], 0, 0, 0);
        }
        __syncthreads();
    }

    #pragma unroll
    for (int nf = 0; nf < 4; ++nf) {
        const int cc = n0 + wn * 64 + nf * 16 + lr;
        const float bb = bias[cc];
        #pragma unroll
        for (int mf = 0; mf < 4; ++mf) {
            #pragma unroll
            for (int r = 0; r < 4; ++r) {
                float x = acc[mf][nf][r] + bb;
                if (RELU) x = fmaxf(x, 0.0f);
                const size_t rr = (size_t)(m0 + wm * 64 + mf * 16 + lg * 4 + r);
                if (OUT_BF16) ((unsigned short*)Cv)[rr * N + cc] = f2bf(x);
                else          ((float*)Cv)[rr * N + cc] = x;
            }
        }
    }
}

// ---------------------------------------------------------------------------
// Workspace layout (ushort elements):
//   Qp : [0        , 8388608 )  -> reused as H1 after attention
//   Kp : [8388608  , 16777216)
//   Vt : [16777216 , 25165824)  (projection z=2 writes [b][h][d][s] directly)
//   Y  : [25165824 , 33554432)
//   W1b: [33554432 , 34603008)
//   W2b: [34603008 , 35651584)
//   qb : [35651584 , 36175872)
//   kb : [36175872 , 36700160)
//   vb : [36700160 , 37224448)
//   Wqb: [37224448 , 37289984)   total ~74.6 MB
// ---------------------------------------------------------------------------
extern "C" void kernel_launch(void* const* d_in, const int* in_sizes, int n_in,
                              void* d_out, int out_size, void* d_ws, size_t ws_size,
                              hipStream_t stream) {
    const float* q  = (const float*)d_in[0];
    const float* k  = (const float*)d_in[1];
    const float* v  = (const float*)d_in[2];
    const float* Wq = (const float*)d_in[3];
    const float* bq = (const float*)d_in[4];
    const float* W1 = (const float*)d_in[5];
    const float* b1 = (const float*)d_in[6];
    const float* W2 = (const float*)d_in[7];
    const float* b2 = (const float*)d_in[8];

    unsigned short* wsu = (unsigned short*)d_ws;
    unsigned short* Qp  = wsu;
    unsigned short* Kp  = wsu + (size_t)8388608;
    unsigned short* Vt  = wsu + (size_t)16777216;
    unsigned short* Y   = wsu + (size_t)25165824;
    unsigned short* W1b = wsu + (size_t)33554432;
    unsigned short* W2b = wsu + (size_t)34603008;
    unsigned short* qb  = wsu + (size_t)35651584;
    unsigned short* kb  = wsu + (size_t)36175872;
    unsigned short* vb  = wsu + (size_t)36700160;
    unsigned short* Wqb = wsu + (size_t)37224448;
    unsigned short* H1  = Qp;   // Qp dead after attention

    dim3 blk(256);

    // q/k/v/Wq conversion (needed by proj); W1/W2 cvt rides inside attn
    cvt_pre<<<dim3(256, 4), blk, 0, stream>>>(q, k, v, Wq, qb, kb, vb, Wqb);

    // folds 1/sqrt(dk)=0.125 and log2(e) into Q so attn uses v_exp_f32 directly
    const float qscale = 0.125f * 1.44269504088896340736f;
    proj_mfma<<<dim3(8, 64, 3), blk, 0, stream>>>(qb, kb, vb, Wqb, bq, Qp, qscale);

    // blocks [0,1024): attention; [1024,2048): W1/W2 bf16 conversion
    attn_v15f<<<2048, blk, 0, stream>>>(Qp, Kp, Vt, Y, W1, W2, W1b, W2b);

    mlp_gemm<true,  true ><<<512, blk, 0, stream>>>(Y,  W1b, b1, H1);
    mlp_gemm<false, false><<<512, blk, 0, stream>>>(H1, W2b, b2, d_out);
}